// Round 1
// baseline (188.076 us; speedup 1.0000x reference)
//
#include <hip/hip_runtime.h>
#include <hip/hip_bf16.h>

typedef __attribute__((ext_vector_type(8))) short s8v;    // 8 bf16
typedef __attribute__((ext_vector_type(4))) short s4v;    // 4 bf16
typedef __attribute__((ext_vector_type(4))) float f4v;    // 4 fp32

__device__ __forceinline__ void g2lds16(const void* g, void* l) {
  __builtin_amdgcn_global_load_lds(
      (__attribute__((address_space(1))) void*)(g),
      (__attribute__((address_space(3))) void*)(l), 16, 0, 0);
}

__device__ __forceinline__ short f2bf(float f) {
  __hip_bfloat16 h = __float2bfloat16(f);
  return *reinterpret_cast<short*>(&h);
}

#define FENCE asm volatile("" ::: "memory")
#define BARRIER do { FENCE; __builtin_amdgcn_s_barrier(); FENCE; } while (0)

// ---------------- K0: fused x->bf16 cvt  +  W transpose->bf16 ----------------
__global__ void k_prep(const float* __restrict__ x, const float* __restrict__ W,
                       __hip_bfloat16* __restrict__ xb, __hip_bfloat16* __restrict__ Wt) {
  int bx = blockIdx.x;
  if (bx < 4096) {
    int i = (bx * 256 + threadIdx.x) * 4;
    float4 v = *(const float4*)(x + i);
    __hip_bfloat16 o[4] = {__float2bfloat16(v.x), __float2bfloat16(v.y),
                           __float2bfloat16(v.z), __float2bfloat16(v.w)};
    *(uint2*)(xb + i) = *(const uint2*)(o);
  } else {
    __shared__ float tile[32][33];
    int r = bx - 4096;            // 0..3071 = 32 x 96
    int rt = r / 96;              // over 1024/32
    int ct = r - rt * 96;         // over 3072/32
    int c0 = ct * 32, r0 = rt * 32;
    int tr = threadIdx.x >> 5, tc = threadIdx.x & 31;
#pragma unroll
    for (int i = 0; i < 32; i += 8)
      tile[tr + i][tc] = W[(size_t)(r0 + tr + i) * 3072 + c0 + tc];
    __syncthreads();
#pragma unroll
    for (int i = 0; i < 32; i += 8)
      Wt[(size_t)(c0 + tr + i) * 1024 + r0 + tc] = __float2bfloat16(tile[tc][tr + i]);
  }
}

// ---------------- K1: GEMM + fused QKV scatter epilogue ----------------
// 256x256 tile, BK=64 (two 32-wide k-sub planes), 8 waves (2m x 4n), 512 thr.
// Single 64KB LDS buffer, in-place pipelined staging with dead-region
// scheduling: 4 phases per K-tile, 16 MFMA/phase, raw s_barrier (no drain),
// counted s_waitcnt vmcnt(1) twice per K-tile, s_setprio(1) around MFMA.
//
// LDS A planes store rows with bits6/7 swapped (phys<->global involution) so
// each 8KB stage unit (128 phys rows) is exactly one dead-region batch:
//   phys [  0..127] of plane s = global quarters q0,q2 (read in h=0 phases)
//   phys [128..255] of plane s = global quarters q1,q3 (read in h=1 phases)
// B planes are stored unpermuted (whole plane is dead after its 2nd phase).
// Bank swizzle (k-slot ^ (row>>1)&3, pre-applied to the global source) is the
// same conflict-free pattern as the previous 128^2 kernel.
//
// Stage batches for tile T (8 x 8KB issues):
//   S1(T): A s0 h0           @ p1-slot of T-1     (1 issue)
//   S2(T): A s0 h1, B s0 x2  @ p2-slot of T-1     (3 issues)
//   S3(T): A s1 h0           @ p3-slot of T-1     (1 issue)
//   S4(T): A s1 h1, B s1 x2  @ p0-slot of T       (3 issues)
// Gates: G2 = vmcnt(1) at p1 tail (S3,S4 of T landed; S1(T+1) may fly)
//        G1 = vmcnt(1) at p3 tail (S1,S2 of T+1 landed; S3(T+1) may fly)
__global__ __launch_bounds__(512, 2) void k_gemm(const __hip_bfloat16* __restrict__ A,
                                                 const __hip_bfloat16* __restrict__ Bt,
                                                 const float* __restrict__ bias,
                                                 __hip_bfloat16* __restrict__ Q,
                                                 __hip_bfloat16* __restrict__ K,
                                                 __hip_bfloat16* __restrict__ Vt) {
  __shared__ __align__(16) __hip_bfloat16 As[2][256 * 32];  // [ksub][physrow*32]
  __shared__ __align__(16) __hip_bfloat16 Bs[2][256 * 32];
  const int tid = threadIdx.x;
  const int lane = tid & 63, wave = tid >> 6;      // 8 waves
  const int m0 = blockIdx.y * 256, n0 = blockIdx.x * 256;
  const int wm = (wave >> 2) * 128;                // wave-row group: 0 / 128
  const int wn = (wave & 3) * 64;                  // wave-col group
  const int lrow = lane & 15, quad = lane >> 4;
  const int key = (lrow >> 1) & 3;
  const int sw8 = (quad ^ key) << 3;               // swizzled k-slot (elems)
  const int aPB = (wave >> 2) * 64;                // A phys base (h adds 128)

  f4v acc[8][4] = {};

  auto stageA = [&](int kt, int s, int hf) {
    int e = hf * 4096 + tid * 8;                   // elem idx in plane
    int p = e >> 5;                                // phys row
    int g = (p & 63) | ((p & 64) << 1) | ((p & 128) >> 1);  // swap bits 6,7
    int oct = (tid & 3) ^ ((p >> 1) & 3);          // pre-swizzled k-octet
    g2lds16(A + (size_t)(m0 + g) * 1024 + kt * 64 + s * 32 + (oct << 3),
            &As[s][e]);
  };
  auto stageB = [&](int kt, int s, int hf) {
    int e = hf * 4096 + tid * 8;
    int p = e >> 5;                                // phys row == global row
    int oct = (tid & 3) ^ ((p >> 1) & 3);
    g2lds16(Bt + (size_t)(n0 + p) * 1024 + kt * 64 + s * 32 + (oct << 3),
            &Bs[s][e]);
  };

  // prologue: stage tile 0 completely; only vmcnt(0) in the kernel
  stageA(0, 0, 0); stageA(0, 0, 1); stageB(0, 0, 0); stageB(0, 0, 1);
  stageA(0, 1, 0); stageA(0, 1, 1); stageB(0, 1, 0); stageB(0, 1, 1);
  asm volatile("s_waitcnt vmcnt(0)" ::: "memory");
  BARRIER;

  for (int t = 0; t < 16; ++t) {
    const int bt = (t < 15) ? t + 1 : 15;          // staged tile (clamped)
    s8v af[4], bfr[4];

    // ---- p0: h=0, s=0 ----
#pragma unroll
    for (int i = 0; i < 4; ++i)
      af[i] = *(const s8v*)(&As[0][(aPB + i * 16 + lrow) * 32 + sw8]);
#pragma unroll
    for (int i = 0; i < 4; ++i)
      bfr[i] = *(const s8v*)(&Bs[0][(wn + i * 16 + lrow) * 32 + sw8]);
    if (t > 0) { stageA(t, 1, 1); stageB(t, 1, 0); stageB(t, 1, 1); }  // S4(t)
    BARRIER;
    __builtin_amdgcn_s_setprio(1);
#pragma unroll
    for (int i = 0; i < 4; ++i)
#pragma unroll
      for (int n = 0; n < 4; ++n)
        acc[i][n] = __builtin_amdgcn_mfma_f32_16x16x32_bf16(af[i], bfr[n], acc[i][n], 0, 0, 0);
    __builtin_amdgcn_s_setprio(0);
    BARRIER;

    // ---- p1: h=1, s=0 (bfr reused) ----
#pragma unroll
    for (int i = 0; i < 4; ++i)
      af[i] = *(const s8v*)(&As[0][(aPB + 128 + i * 16 + lrow) * 32 + sw8]);
    stageA(bt, 0, 0);                              // S1(t+1)
    BARRIER;
    __builtin_amdgcn_s_setprio(1);
#pragma unroll
    for (int i = 0; i < 4; ++i)
#pragma unroll
      for (int n = 0; n < 4; ++n)
        acc[4 + i][n] = __builtin_amdgcn_mfma_f32_16x16x32_bf16(af[i], bfr[n], acc[4 + i][n], 0, 0, 0);
    __builtin_amdgcn_s_setprio(0);
    asm volatile("s_waitcnt vmcnt(1)" ::: "memory");  // G2: S3(t),S4(t) landed
    BARRIER;

    // ---- p2: h=0, s=1 ----
#pragma unroll
    for (int i = 0; i < 4; ++i)
      af[i] = *(const s8v*)(&As[1][(aPB + i * 16 + lrow) * 32 + sw8]);
#pragma unroll
    for (int i = 0; i < 4; ++i)
      bfr[i] = *(const s8v*)(&Bs[1][(wn + i * 16 + lrow) * 32 + sw8]);
    stageA(bt, 0, 1); stageB(bt, 0, 0); stageB(bt, 0, 1);  // S2(t+1)
    BARRIER;
    __builtin_amdgcn_s_setprio(1);
#pragma unroll
    for (int i = 0; i < 4; ++i)
#pragma unroll
      for (int n = 0; n < 4; ++n)
        acc[i][n] = __builtin_amdgcn_mfma_f32_16x16x32_bf16(af[i], bfr[n], acc[i][n], 0, 0, 0);
    __builtin_amdgcn_s_setprio(0);
    BARRIER;

    // ---- p3: h=1, s=1 ----
#pragma unroll
    for (int i = 0; i < 4; ++i)
      af[i] = *(const s8v*)(&As[1][(aPB + 128 + i * 16 + lrow) * 32 + sw8]);
    stageA(bt, 1, 0);                              // S3(t+1)
    BARRIER;
    __builtin_amdgcn_s_setprio(1);
#pragma unroll
    for (int i = 0; i < 4; ++i)
#pragma unroll
      for (int n = 0; n < 4; ++n)
        acc[4 + i][n] = __builtin_amdgcn_mfma_f32_16x16x32_bf16(af[i], bfr[n], acc[4 + i][n], 0, 0, 0);
    __builtin_amdgcn_s_setprio(0);
    asm volatile("s_waitcnt vmcnt(1)" ::: "memory");  // G1: S1,S2(t+1) landed
    BARRIER;
  }

  // epilogue: per-row destination decode, d-packed 8B stores for Q/K
  const int cw = n0 + wn;            // multiple of 64 -> c10 wave-uniform
  const int c10 = cw >> 10;          // 0..2
  const int d0 = (cw & 1023) >> 4;   // multiple of 4
  const int h = lrow;
  float bv[4];
#pragma unroll
  for (int ni = 0; ni < 4; ++ni) bv[ni] = bias[cw + ni * 16 + lrow];

#pragma unroll
  for (int mi = 0; mi < 8; ++mi) {
    int rbase = m0 + wm + mi * 16 + quad * 4;
#pragma unroll
    for (int reg = 0; reg < 4; ++reg) {
      int rr = rbase + reg;
      int u = 3 * rr + c10;
      int s = u >> 12;
      int b = (u >> 11) & 1;
      int tt = u & 2047;
      if (s < 2) {
        __hip_bfloat16* dst = (s == 0) ? Q : K;
        s4v pk;
#pragma unroll
        for (int ni = 0; ni < 4; ++ni) pk[ni] = f2bf(acc[mi][ni][reg] + bv[ni]);
        *(s4v*)(dst + ((size_t)(b * 16 + h) * 2048 + tt) * 64 + d0) = pk;
      } else {
#pragma unroll
        for (int ni = 0; ni < 4; ++ni)
          Vt[((size_t)(b * 16 + h) * 64 + d0 + ni) * 2048 + tt] =
              __float2bfloat16(acc[mi][ni][reg] + bv[ni]);
      }
    }
  }
}

// ---------------- K2: causal flash attention ----------------
// (unchanged from previous round)
__global__ __launch_bounds__(256, 3) void k_attn(const __hip_bfloat16* __restrict__ Q,
                                                 const __hip_bfloat16* __restrict__ K,
                                                 const __hip_bfloat16* __restrict__ Vt,
                                                 float* __restrict__ out) {
  __shared__ __align__(16) char lds[2][16384];  // per buf: K tile 8KB | V tile 8KB

  const int tid = threadIdx.x;
  const int lane = tid & 63, w = tid >> 6;
  const int l = lane & 15, q = lane >> 4, lx = l & 7;

  const int bid = blockIdx.x;           // 1024 blocks
  const int xcd = bid & 7;
  const int idx = bid >> 3;             // 0..127
  const int bh = xcd + 8 * (idx & 3);   // 4 bh per XCD -> 2MB K+V in its L2
  const int qb = 31 - (idx >> 2);       // heavy blocks first; tiles 0..qb

  const char* Kb = (const char*)(K + (size_t)bh * 131072);
  const char* Vb = (const char*)(Vt + (size_t)bh * 131072);
  const __hip_bfloat16* Qp = Q + (size_t)bh * 131072 + (size_t)qb * 4096;

  // Q fragment (load once): B[n=t][k], t = qb*64 + w*16 + l
  s8v Qf[2];
#pragma unroll
  for (int kh = 0; kh < 2; ++kh)
    Qf[kh] = *(const s8v*)(Qp + (size_t)(w * 16 + l) * 64 + kh * 32 + q * 8);

  f4v O[4] = {};
  float m = -INFINITY, lsum = 0.f;
  const float c1 = 0.125f * 1.44269504088896f;  // scale * log2(e)
  const int tg = qb * 64 + w * 16 + l;          // this lane's global Q row

  auto stage = [&](int j, char* buf) {
#pragma unroll
    for (int c = 0; c < 4; ++c) {
      int chunk = w * 4 + c;            // 0..15
      int ls = chunk * 64 + lane;       // 16B-slot index
      if (chunk < 8) {                  // K tile: LDS[row][kb] = K[row][kb ^ (row&7)]
        int row = ls >> 3, kb = ls & 7;
        g2lds16(Kb + (size_t)j * 8192 + row * 128 + ((kb ^ (row & 7)) << 4),
                buf + ls * 16);
      } else {                          // V tile: LDS[d][kb] = V^T[d][kb ^ (d&7)]
        int ls2 = ls - 512;
        int d = ls2 >> 3, kb = ls2 & 7;
        g2lds16(Vb + (size_t)d * 4096 + (size_t)j * 128 + ((kb ^ (d & 7)) << 4),
                buf + 8192 + ls2 * 16);
      }
    }
  };

  stage(0, lds[0]);
  __syncthreads();

  for (int j = 0; j <= qb; ++j) {
    const char* Kl = lds[j & 1];
    const char* Vl = Kl + 8192;
    if (j < qb) stage(j + 1, lds[(j + 1) & 1]);

    // S^T: A = K rows (m = s_local), B = Q (n = t)
    f4v S[4];
#pragma unroll
    for (int nt = 0; nt < 4; ++nt) {
      const char* rowp = Kl + (nt * 16 + l) * 128;
      s8v k0 = *(const s8v*)(rowp + ((q ^ lx) << 4));
      s8v k1 = *(const s8v*)(rowp + (((4 + q) ^ lx) << 4));
      f4v z = {0.f, 0.f, 0.f, 0.f};
      z = __builtin_amdgcn_mfma_f32_16x16x32_bf16(k0, Qf[0], z, 0, 0, 0);
      z = __builtin_amdgcn_mfma_f32_16x16x32_bf16(k1, Qf[1], z, 0, 0, 0);
      S[nt] = z;
    }

    float p2[4][4];
#pragma unroll
    for (int nt = 0; nt < 4; ++nt)
#pragma unroll
      for (int r = 0; r < 4; ++r) p2[nt][r] = S[nt][r] * c1;
    if (j == qb) {
#pragma unroll
      for (int nt = 0; nt < 4; ++nt)
#pragma unroll
        for (int r = 0; r < 4; ++r)
          if (j * 64 + nt * 16 + q * 4 + r > tg) p2[nt][r] = -1e30f;
    }

    float mx = p2[0][0];
#pragma unroll
    for (int nt = 0; nt < 4; ++nt)
#pragma unroll
      for (int r = 0; r < 4; ++r) mx = fmaxf(mx, p2[nt][r]);
    mx = fmaxf(mx, __shfl_xor(mx, 16));
    mx = fmaxf(mx, __shfl_xor(mx, 32));
    float mn = fmaxf(m, mx);
    float alpha = exp2f(m - mn);
    m = mn;

    float rs = 0.f;
    s4v Pf[4];
#pragma unroll
    for (int nt = 0; nt < 4; ++nt)
#pragma unroll
      for (int r = 0; r < 4; ++r) {
        float e = exp2f(p2[nt][r] - mn);
        rs += e;
        Pf[nt][r] = f2bf(e);
      }
    rs += __shfl_xor(rs, 16);
    rs += __shfl_xor(rs, 32);
    lsum = lsum * alpha + rs;
#pragma unroll
    for (int dt = 0; dt < 4; ++dt) O[dt] *= alpha;

    // PV: A = V^T rows (m = d), B = P (n = t, k = s in C-layout regs)
#pragma unroll
    for (int sc = 0; sc < 4; ++sc) {
      int so = ((sc * 2 + (q >> 1)) ^ lx) * 16 + (q & 1) * 8;
#pragma unroll
      for (int dt = 0; dt < 4; ++dt) {
        s4v vv = *(const s4v*)(Vl + (dt * 16 + l) * 128 + so);
        O[dt] = __builtin_amdgcn_mfma_f32_16x16x16bf16_1k(vv, Pf[sc], O[dt], 0, 0, 0);
      }
    }
    __syncthreads();  // staging of j+1 drained; all waves done with buf (j&1)
  }

  // epilogue: lane holds row t = tg, cols d = dt*16 + q*4 + r  -> float4 stores
  float inv = 1.f / lsum;
  int b = bh >> 4, h = bh & 15;
  float* ob = out + ((size_t)b * 2048 + tg) * 1024 + h * 64;
#pragma unroll
  for (int dt = 0; dt < 4; ++dt) {
    f4v val = O[dt] * inv;
    *(f4v*)(ob + dt * 16 + q * 4) = val;
  }
}

extern "C" void kernel_launch(void* const* d_in, const int* in_sizes, int n_in,
                              void* d_out, int out_size, void* d_ws, size_t ws_size,
                              hipStream_t stream) {
  const float* x = (const float*)d_in[0];     // [2,2048,1024]
  const float* W = (const float*)d_in[1];     // [1024,3072]
  const float* bias = (const float*)d_in[2];  // [3072]
  float* out = (float*)d_out;                 // [2,2048,1024]

  char* ws = (char*)d_ws;
  __hip_bfloat16* xb = (__hip_bfloat16*)ws;                    // 8,388,608 B
  __hip_bfloat16* Wt = (__hip_bfloat16*)(ws + 8388608);        // 6,291,456 B
  __hip_bfloat16* Qg = (__hip_bfloat16*)(ws + 14680064);       // 8,388,608 B
  __hip_bfloat16* Kg = (__hip_bfloat16*)(ws + 23068672);       // 8,388,608 B
  __hip_bfloat16* Vt = (__hip_bfloat16*)(ws + 31457280);       // 8,388,608 B

  k_prep<<<7168, 256, 0, stream>>>(x, W, xb, Wt);
  k_gemm<<<dim3(12, 16), 512, 0, stream>>>(xb, Wt, bias, Qg, Kg, Vt);
  k_attn<<<1024, 256, 0, stream>>>(Qg, Kg, Vt, out);
}